// Round 11
// baseline (932.162 us; speedup 1.0000x reference)
//
#include <hip/hip_runtime.h>

// PooledSSIMLoss: x,y (16,3,512,512) fp32, 11x11 VALID box filters,
// SSIM map (48,502,502) -> scalar 1 - mean.
//
// R7 (resubmit x4; four GPUAcquisitionTimeouts): R5 lane-autonomous
// structure (no LDS / barriers / shuffles; 8 own cols + 10 halo cols per
// lane, in-register 11-tap), with 2x the wave supply: SEG 12->6 gives 4032
// single-wave blocks (~4 waves/SIMD) to hide the ~900-cycle load->use
// latency that R5's 2 waves/SIMD could not.
// __launch_bounds__(64,4) caps VGPR at 128 (R5 used 124).

#define WIN     11
#define IMG     512
#define PLSZ    (IMG * IMG)
#define OUTW    502
#define SEG     6
#define NSEG    84             // ceil(502/6)
#define NPLANES 48
#define NBLK    (NSEG * NPLANES)   // 4032

#define C1S   1.4641f          // (0.01)^2 * 121^2
#define C2S   13.1769f         // (0.03)^2 * 121^2
#define EPS4  2.1434881f       // 1e-8 * 121^4

__global__ __launch_bounds__(64) void ssim_zero(double* acc) {
    if (threadIdx.x == 0) acc[0] = 0.0;
}

__global__ __launch_bounds__(64, 4) void ssim_main(const float* __restrict__ x,
                                                   const float* __restrict__ y,
                                                   double* __restrict__ part,
                                                   int mode) {
    const int lane = threadIdx.x;          // 0..63
    const int id   = blockIdx.x;           // 0..4031
    // XCD swizzle: id%8 ~ XCD; give each plane a fixed XCD residue.
    const int q8    = id >> 3;             // 0..503
    const int plane = (id & 7) + 8 * (q8 / NSEG);   // 0..47
    const int seg   = q8 % NSEG;                    // 0..83

    const int o0 = seg * SEG;
    const int o1 = (o0 + SEG < OUTW) ? (o0 + SEG) : OUTW;
    const int r0 = o0;
    const int r1 = o1 + WIN - 2;           // <= 511

    const int c0 = 8 * lane;               // first output col of this lane
    // window cols c0..c0+17; clamp in-row (clamped lanes feed masked outputs)
    const int a0 = c0;
    const int a1 = c0 + 4;
    const int a2 = (c0 + 8  < 508) ? (c0 + 8)  : 508;
    const int a3 = (c0 + 12 < 508) ? (c0 + 12) : 508;
    const int a4 = (c0 + 16 < 510) ? (c0 + 16) : 510;

    const float* xp = x + plane * PLSZ;
    const float* yp = y + plane * PLSZ;

#define LOADROW(P, R, v0, v1, v2, v3, v4)                        \
    { const float* rp_ = (P) + ((R) << 9);                       \
      v0 = *(const float4*)(rp_ + a0);                           \
      v1 = *(const float4*)(rp_ + a1);                           \
      v2 = *(const float4*)(rp_ + a2);                           \
      v3 = *(const float4*)(rp_ + a3);                           \
      v4 = *(const float2*)(rp_ + a4); }

#define UNPACK(v0, v1, v2, v3, v4, arr)                          \
    { arr[0]=v0.x;  arr[1]=v0.y;  arr[2]=v0.z;  arr[3]=v0.w;     \
      arr[4]=v1.x;  arr[5]=v1.y;  arr[6]=v1.z;  arr[7]=v1.w;     \
      arr[8]=v2.x;  arr[9]=v2.y;  arr[10]=v2.z; arr[11]=v2.w;    \
      arr[12]=v3.x; arr[13]=v3.y; arr[14]=v3.z; arr[15]=v3.w;    \
      arr[16]=v4.x; arr[17]=v4.y; }

    float Vx[18], Vy[18], Vxx[18], Vyy[18], Vxy[18];
#pragma unroll
    for (int j = 0; j < 18; ++j) {
        Vx[j] = 0.f; Vy[j] = 0.f; Vxx[j] = 0.f; Vyy[j] = 0.f; Vxy[j] = 0.f;
    }

    const float4 z4 = make_float4(0.f, 0.f, 0.f, 0.f);
    const float2 z2 = make_float2(0.f, 0.f);
    // current-new (row r), current-old (row r-11), and in-flight next of each
    float4 cnx0, cnx1, cnx2, cnx3; float2 cnx4;
    float4 cny0, cny1, cny2, cny3; float2 cny4;
    float4 cox0 = z4, cox1 = z4, cox2 = z4, cox3 = z4; float2 cox4 = z2;
    float4 coy0 = z4, coy1 = z4, coy2 = z4, coy3 = z4; float2 coy4 = z2;
    float4 nnx0 = z4, nnx1 = z4, nnx2 = z4, nnx3 = z4; float2 nnx4 = z2;
    float4 nny0 = z4, nny1 = z4, nny2 = z4, nny3 = z4; float2 nny4 = z2;
    float4 nox0 = z4, nox1 = z4, nox2 = z4, nox3 = z4; float2 nox4 = z2;
    float4 noy0 = z4, noy1 = z4, noy2 = z4, noy3 = z4; float2 noy4 = z2;

    LOADROW(xp, r0, cnx0, cnx1, cnx2, cnx3, cnx4)
    LOADROW(yp, r0, cny0, cny1, cny2, cny3, cny4)

    float lsum = 0.f;

    for (int r = r0; r <= r1; ++r) {
        // ---- issue next-iteration loads (consumed at iter r+1) ----
        if (r < r1) {
            LOADROW(xp, r + 1, nnx0, nnx1, nnx2, nnx3, nnx4)
            LOADROW(yp, r + 1, nny0, nny1, nny2, nny3, nny4)
        }
        const int ro = r + 1 - WIN;        // old row subtracted at iter r+1
        if (ro >= r0) {
            LOADROW(xp, ro, nox0, nox1, nox2, nox3, nox4)
            LOADROW(yp, ro, noy0, noy1, noy2, noy3, noy4)
        }

        // ---- vertical running sums: add new row r ----
        {
            float xn[18], yn[18];
            UNPACK(cnx0, cnx1, cnx2, cnx3, cnx4, xn)
            UNPACK(cny0, cny1, cny2, cny3, cny4, yn)
#pragma unroll
            for (int j = 0; j < 18; ++j) {
                Vx[j] += xn[j];
                Vy[j] += yn[j];
                Vxx[j] = fmaf(xn[j], xn[j], Vxx[j]);
                Vyy[j] = fmaf(yn[j], yn[j], Vyy[j]);
                Vxy[j] = fmaf(xn[j], yn[j], Vxy[j]);
            }
        }
        // ---- subtract old row r-11 ----
        if (r - r0 >= WIN) {
            float xo[18], yo[18];
            UNPACK(cox0, cox1, cox2, cox3, cox4, xo)
            UNPACK(coy0, coy1, coy2, coy3, coy4, yo)
#pragma unroll
            for (int j = 0; j < 18; ++j) {
                Vx[j] -= xo[j];
                Vy[j] -= yo[j];
                Vxx[j] = fmaf(-xo[j], xo[j], Vxx[j]);
                Vyy[j] = fmaf(-yo[j], yo[j], Vyy[j]);
                Vxy[j] = fmaf(-xo[j], yo[j], Vxy[j]);
            }
        }

        // ---- emission: in-register horizontal 11-tap + SSIM, row r-10 ----
        if (r - r0 >= WIN - 1) {
#define SUM11(V, s)                                                       \
            { float t0_ = V[0] + V[1], t1_ = V[2] + V[3];                 \
              float t2_ = V[4] + V[5], t3_ = V[6] + V[7];                 \
              float t4_ = V[8] + V[9];                                    \
              s = ((t0_ + t1_) + (t2_ + t3_)) + (t4_ + V[10]); }
            float s0, s1, s2, s3, s4;
            SUM11(Vx,  s0)
            SUM11(Vy,  s1)
            SUM11(Vxx, s2)
            SUM11(Vyy, s3)
            SUM11(Vxy, s4)
#undef SUM11
#pragma unroll
            for (int j = 0; j < 8; ++j) {
                const float X = s0, Y = s1, XX = s2, YY = s3, XY = s4;
                const float x2 = X * X, y2 = Y * Y, xy = X * Y;
                // scaled domain: all quantities carry a 121^2 factor
                const float A  = fmaf(2.f, xy, C1S);
                const float B  = fmaf(2.f, fmaf(121.f, XY, -xy), C2S);
                const float Cc = (x2 + y2) + C1S;
                const float sx = fmaxf(fmaf(121.f, XX, -x2), 0.f);
                const float sy = fmaxf(fmaf(121.f, YY, -y2), 0.f);
                const float D  = (sx + sy) + C2S;
                const float den = fmaf(Cc, D, EPS4);
                float rr = __builtin_amdgcn_rcpf(den);
                rr = rr * (2.f - den * rr);            // 1 Newton step
                if (c0 + j < OUTW) lsum = fmaf(A * B, rr, lsum);
                if (j < 7) {
                    s0 += Vx[j + 11]  - Vx[j];
                    s1 += Vy[j + 11]  - Vy[j];
                    s2 += Vxx[j + 11] - Vxx[j];
                    s3 += Vyy[j + 11] - Vyy[j];
                    s4 += Vxy[j + 11] - Vxy[j];
                }
            }
        }

        // ---- rotate pipelines ----
        cnx0 = nnx0; cnx1 = nnx1; cnx2 = nnx2; cnx3 = nnx3; cnx4 = nnx4;
        cny0 = nny0; cny1 = nny1; cny2 = nny2; cny3 = nny3; cny4 = nny4;
        cox0 = nox0; cox1 = nox1; cox2 = nox2; cox3 = nox3; cox4 = nox4;
        coy0 = noy0; coy1 = noy1; coy2 = noy2; coy3 = noy3; coy4 = noy4;
    }
#undef LOADROW
#undef UNPACK

    // ---- wave reduction -> partials ----
#pragma unroll
    for (int off = 32; off > 0; off >>= 1) lsum += __shfl_down(lsum, off, 64);
    if (lane == 0) {
        if (mode == 0) part[id] = (double)lsum;
        else           atomicAdd(part, (double)lsum);
    }
}

__global__ __launch_bounds__(256) void ssim_final(const double* __restrict__ part,
                                                  int n, float* __restrict__ out) {
    __shared__ double s[4];
    double v = 0.0;
    for (int i = threadIdx.x; i < n; i += 256) v += part[i];
#pragma unroll
    for (int off = 32; off > 0; off >>= 1) v += __shfl_down(v, off, 64);
    if ((threadIdx.x & 63) == 0) s[threadIdx.x >> 6] = v;
    __syncthreads();
    if (threadIdx.x == 0) {
        double tot = (s[0] + s[1]) + (s[2] + s[3]);
        const double N = (double)NPLANES * OUTW * OUTW;   // 12,096,192
        out[0] = 1.0f - (float)(tot / N);
    }
}

extern "C" void kernel_launch(void* const* d_in, const int* in_sizes, int n_in,
                              void* d_out, int out_size, void* d_ws, size_t ws_size,
                              hipStream_t stream) {
    const float* x = (const float*)d_in[0];
    const float* y = (const float*)d_in[1];
    float* out = (float*)d_out;
    double* part = (double*)d_ws;

    if (ws_size >= (size_t)NBLK * sizeof(double)) {
        ssim_main<<<dim3(NBLK), dim3(64), 0, stream>>>(x, y, part, 0);
        ssim_final<<<dim3(1), dim3(256), 0, stream>>>(part, NBLK, out);
    } else {
        ssim_zero<<<dim3(1), dim3(64), 0, stream>>>(part);
        ssim_main<<<dim3(NBLK), dim3(64), 0, stream>>>(x, y, part, 1);
        ssim_final<<<dim3(1), dim3(256), 0, stream>>>(part, 1, out);
    }
}

// Round 13
// 151.059 us; speedup vs baseline: 6.1709x; 6.1709x over previous
//
#include <hip/hip_runtime.h>

// PooledSSIMLoss: x,y (16,3,512,512) fp32, 11x11 VALID box filters,
// SSIM map (48,502,502) -> scalar 1 - mean.
//
// R12 (resubmit; GPUAcquisitionTimeout): R7 with the launch_bounds
// occupancy arg REMOVED. (64,4) made hipcc cap the allocator at 64 VGPR ->
// ~124 live values spilled to scratch -> 3.5 GB of HBM spill traffic,
// 843 us, VALUBusy 3%. Plain __launch_bounds__(64) compiles this body to
// ~124 VGPR (R5-measured), which still admits 4 waves/SIMD; SEG=6's 4032
// waves ~ 3.94/SIMD fill it. Structure: lane-autonomous, no LDS/barriers/
// shuffles; 8 own cols + 10 halo cols per lane; in-register 11-tap; loads
// pipelined 1 row ahead.

#define WIN     11
#define IMG     512
#define PLSZ    (IMG * IMG)
#define OUTW    502
#define SEG     6
#define NSEG    84             // ceil(502/6)
#define NPLANES 48
#define NBLK    (NSEG * NPLANES)   // 4032

#define C1S   1.4641f          // (0.01)^2 * 121^2
#define C2S   13.1769f         // (0.03)^2 * 121^2
#define EPS4  2.1434881f       // 1e-8 * 121^4

__global__ __launch_bounds__(64) void ssim_zero(double* acc) {
    if (threadIdx.x == 0) acc[0] = 0.0;
}

__global__ __launch_bounds__(64) void ssim_main(const float* __restrict__ x,
                                                const float* __restrict__ y,
                                                double* __restrict__ part,
                                                int mode) {
    const int lane = threadIdx.x;          // 0..63
    const int id   = blockIdx.x;           // 0..4031
    // XCD swizzle: id%8 ~ XCD; give each plane a fixed XCD residue.
    const int q8    = id >> 3;             // 0..503
    const int plane = (id & 7) + 8 * (q8 / NSEG);   // 0..47
    const int seg   = q8 % NSEG;                    // 0..83

    const int o0 = seg * SEG;
    const int o1 = (o0 + SEG < OUTW) ? (o0 + SEG) : OUTW;
    const int r0 = o0;
    const int r1 = o1 + WIN - 2;           // <= 511

    const int c0 = 8 * lane;               // first output col of this lane
    // window cols c0..c0+17; clamp in-row (clamped lanes feed masked outputs)
    const int a0 = c0;
    const int a1 = c0 + 4;
    const int a2 = (c0 + 8  < 508) ? (c0 + 8)  : 508;
    const int a3 = (c0 + 12 < 508) ? (c0 + 12) : 508;
    const int a4 = (c0 + 16 < 510) ? (c0 + 16) : 510;

    const float* xp = x + plane * PLSZ;
    const float* yp = y + plane * PLSZ;

#define LOADROW(P, R, v0, v1, v2, v3, v4)                        \
    { const float* rp_ = (P) + ((R) << 9);                       \
      v0 = *(const float4*)(rp_ + a0);                           \
      v1 = *(const float4*)(rp_ + a1);                           \
      v2 = *(const float4*)(rp_ + a2);                           \
      v3 = *(const float4*)(rp_ + a3);                           \
      v4 = *(const float2*)(rp_ + a4); }

#define UNPACK(v0, v1, v2, v3, v4, arr)                          \
    { arr[0]=v0.x;  arr[1]=v0.y;  arr[2]=v0.z;  arr[3]=v0.w;     \
      arr[4]=v1.x;  arr[5]=v1.y;  arr[6]=v1.z;  arr[7]=v1.w;     \
      arr[8]=v2.x;  arr[9]=v2.y;  arr[10]=v2.z; arr[11]=v2.w;    \
      arr[12]=v3.x; arr[13]=v3.y; arr[14]=v3.z; arr[15]=v3.w;    \
      arr[16]=v4.x; arr[17]=v4.y; }

    float Vx[18], Vy[18], Vxx[18], Vyy[18], Vxy[18];
#pragma unroll
    for (int j = 0; j < 18; ++j) {
        Vx[j] = 0.f; Vy[j] = 0.f; Vxx[j] = 0.f; Vyy[j] = 0.f; Vxy[j] = 0.f;
    }

    const float4 z4 = make_float4(0.f, 0.f, 0.f, 0.f);
    const float2 z2 = make_float2(0.f, 0.f);
    // current-new (row r), current-old (row r-11), and in-flight next of each
    float4 cnx0, cnx1, cnx2, cnx3; float2 cnx4;
    float4 cny0, cny1, cny2, cny3; float2 cny4;
    float4 cox0 = z4, cox1 = z4, cox2 = z4, cox3 = z4; float2 cox4 = z2;
    float4 coy0 = z4, coy1 = z4, coy2 = z4, coy3 = z4; float2 coy4 = z2;
    float4 nnx0 = z4, nnx1 = z4, nnx2 = z4, nnx3 = z4; float2 nnx4 = z2;
    float4 nny0 = z4, nny1 = z4, nny2 = z4, nny3 = z4; float2 nny4 = z2;
    float4 nox0 = z4, nox1 = z4, nox2 = z4, nox3 = z4; float2 nox4 = z2;
    float4 noy0 = z4, noy1 = z4, noy2 = z4, noy3 = z4; float2 noy4 = z2;

    LOADROW(xp, r0, cnx0, cnx1, cnx2, cnx3, cnx4)
    LOADROW(yp, r0, cny0, cny1, cny2, cny3, cny4)

    float lsum = 0.f;

    for (int r = r0; r <= r1; ++r) {
        // ---- issue next-iteration loads (consumed at iter r+1) ----
        if (r < r1) {
            LOADROW(xp, r + 1, nnx0, nnx1, nnx2, nnx3, nnx4)
            LOADROW(yp, r + 1, nny0, nny1, nny2, nny3, nny4)
        }
        const int ro = r + 1 - WIN;        // old row subtracted at iter r+1
        if (ro >= r0) {
            LOADROW(xp, ro, nox0, nox1, nox2, nox3, nox4)
            LOADROW(yp, ro, noy0, noy1, noy2, noy3, noy4)
        }

        // ---- vertical running sums: add new row r ----
        {
            float xn[18], yn[18];
            UNPACK(cnx0, cnx1, cnx2, cnx3, cnx4, xn)
            UNPACK(cny0, cny1, cny2, cny3, cny4, yn)
#pragma unroll
            for (int j = 0; j < 18; ++j) {
                Vx[j] += xn[j];
                Vy[j] += yn[j];
                Vxx[j] = fmaf(xn[j], xn[j], Vxx[j]);
                Vyy[j] = fmaf(yn[j], yn[j], Vyy[j]);
                Vxy[j] = fmaf(xn[j], yn[j], Vxy[j]);
            }
        }
        // ---- subtract old row r-11 ----
        if (r - r0 >= WIN) {
            float xo[18], yo[18];
            UNPACK(cox0, cox1, cox2, cox3, cox4, xo)
            UNPACK(coy0, coy1, coy2, coy3, coy4, yo)
#pragma unroll
            for (int j = 0; j < 18; ++j) {
                Vx[j] -= xo[j];
                Vy[j] -= yo[j];
                Vxx[j] = fmaf(-xo[j], xo[j], Vxx[j]);
                Vyy[j] = fmaf(-yo[j], yo[j], Vyy[j]);
                Vxy[j] = fmaf(-xo[j], yo[j], Vxy[j]);
            }
        }

        // ---- emission: in-register horizontal 11-tap + SSIM, row r-10 ----
        if (r - r0 >= WIN - 1) {
#define SUM11(V, s)                                                       \
            { float t0_ = V[0] + V[1], t1_ = V[2] + V[3];                 \
              float t2_ = V[4] + V[5], t3_ = V[6] + V[7];                 \
              float t4_ = V[8] + V[9];                                    \
              s = ((t0_ + t1_) + (t2_ + t3_)) + (t4_ + V[10]); }
            float s0, s1, s2, s3, s4;
            SUM11(Vx,  s0)
            SUM11(Vy,  s1)
            SUM11(Vxx, s2)
            SUM11(Vyy, s3)
            SUM11(Vxy, s4)
#undef SUM11
#pragma unroll
            for (int j = 0; j < 8; ++j) {
                const float X = s0, Y = s1, XX = s2, YY = s3, XY = s4;
                const float x2 = X * X, y2 = Y * Y, xy = X * Y;
                // scaled domain: all quantities carry a 121^2 factor
                const float A  = fmaf(2.f, xy, C1S);
                const float B  = fmaf(2.f, fmaf(121.f, XY, -xy), C2S);
                const float Cc = (x2 + y2) + C1S;
                const float sx = fmaxf(fmaf(121.f, XX, -x2), 0.f);
                const float sy = fmaxf(fmaf(121.f, YY, -y2), 0.f);
                const float D  = (sx + sy) + C2S;
                const float den = fmaf(Cc, D, EPS4);
                float rr = __builtin_amdgcn_rcpf(den);
                rr = rr * (2.f - den * rr);            // 1 Newton step
                if (c0 + j < OUTW) lsum = fmaf(A * B, rr, lsum);
                if (j < 7) {
                    s0 += Vx[j + 11]  - Vx[j];
                    s1 += Vy[j + 11]  - Vy[j];
                    s2 += Vxx[j + 11] - Vxx[j];
                    s3 += Vyy[j + 11] - Vyy[j];
                    s4 += Vxy[j + 11] - Vxy[j];
                }
            }
        }

        // ---- rotate pipelines ----
        cnx0 = nnx0; cnx1 = nnx1; cnx2 = nnx2; cnx3 = nnx3; cnx4 = nnx4;
        cny0 = nny0; cny1 = nny1; cny2 = nny2; cny3 = nny3; cny4 = nny4;
        cox0 = nox0; cox1 = nox1; cox2 = nox2; cox3 = nox3; cox4 = nox4;
        coy0 = noy0; coy1 = noy1; coy2 = noy2; coy3 = noy3; coy4 = noy4;
    }
#undef LOADROW
#undef UNPACK

    // ---- wave reduction -> partials ----
#pragma unroll
    for (int off = 32; off > 0; off >>= 1) lsum += __shfl_down(lsum, off, 64);
    if (lane == 0) {
        if (mode == 0) part[id] = (double)lsum;
        else           atomicAdd(part, (double)lsum);
    }
}

__global__ __launch_bounds__(256) void ssim_final(const double* __restrict__ part,
                                                  int n, float* __restrict__ out) {
    __shared__ double s[4];
    double v = 0.0;
    for (int i = threadIdx.x; i < n; i += 256) v += part[i];
#pragma unroll
    for (int off = 32; off > 0; off >>= 1) v += __shfl_down(v, off, 64);
    if ((threadIdx.x & 63) == 0) s[threadIdx.x >> 6] = v;
    __syncthreads();
    if (threadIdx.x == 0) {
        double tot = (s[0] + s[1]) + (s[2] + s[3]);
        const double N = (double)NPLANES * OUTW * OUTW;   // 12,096,192
        out[0] = 1.0f - (float)(tot / N);
    }
}

extern "C" void kernel_launch(void* const* d_in, const int* in_sizes, int n_in,
                              void* d_out, int out_size, void* d_ws, size_t ws_size,
                              hipStream_t stream) {
    const float* x = (const float*)d_in[0];
    const float* y = (const float*)d_in[1];
    float* out = (float*)d_out;
    double* part = (double*)d_ws;

    if (ws_size >= (size_t)NBLK * sizeof(double)) {
        ssim_main<<<dim3(NBLK), dim3(64), 0, stream>>>(x, y, part, 0);
        ssim_final<<<dim3(1), dim3(256), 0, stream>>>(part, NBLK, out);
    } else {
        ssim_zero<<<dim3(1), dim3(64), 0, stream>>>(part);
        ssim_main<<<dim3(NBLK), dim3(64), 0, stream>>>(x, y, part, 1);
        ssim_final<<<dim3(1), dim3(256), 0, stream>>>(part, 1, out);
    }
}